// Round 20
// baseline (119.954 us; speedup 1.0000x reference)
//
#include <hip/hip_runtime.h>

// QuantizeEMAReset forward (eval): VQ quantize + commit loss + perplexity/usage.
// z: [16,4096,64] fp32 -> N=65536 tokens, C=64. codebook: [1024,64] fp32.
// out: [z_q_bar (4194304 f32), commit_loss, ppl, usage] flat.
//
// R20: recombination of the proven-fastest pieces, no new machinery:
//  - quant: R12's kernel VERBATIM (4-slot x 2-tile ring, 3 groups in flight,
//    vmcnt(4); d1/d2/idx1 + margin flag list). R12's quant measured ~58-61us
//    (total 322 - final 258 - prep 3), fastest of 19 rounds; passed absmax 0.0.
//  - rescue: R11's wave-per-flag exact-fp32 kernel VERBATIM, but 512 blocks
//    (2048 waves >= nf~1000-2000 -> <=1 flag/wave; R11's 64-block run was
//    parallelism-starved). Patches out/counts/loss with the proven chains.
//  - final: R13's reduce-only shuffle trees.
// MARGIN 1e-3 (R5/R13-proven vs ~2e-4 fp16-split error).
// 2-token-set / 32x32 register profiles remain quarantined (R9/R10/R15).
//
// ws float-index map:
//   [0,1024)       cnorm
//   [1024,2048)    counts
//   [2048,3072)    loss partials (1024 quant blocks)
//   3072           nflag (int)
//   [3073,19457)   flag list (int: tok | idx<<16)
//   [20480,86016)  cbhl tile stream: 64 tiles x 2048 halves (hi 1KB | lo 1KB)

typedef _Float16 half8 __attribute__((ext_vector_type(8)));
typedef float f32x4 __attribute__((ext_vector_type(4)));

#define NTOK 65536
#define KCODE 1024
#define OUT_SCALARS 4194304
#define MARGIN 1e-3f
#define FLAG_CAP 16384

#define WS_CNT   1024
#define WS_LOSS  2048
#define WS_NFLAG 3072
#define WS_FLAGS 3073
#define WS_CBHL  20480

static __device__ __forceinline__ unsigned int order_key(float f) {
    unsigned int u = __float_as_uint(f);
    unsigned int mask = (u >> 31) ? 0xFFFFFFFFu : 0x80000000u;
    return u ^ mask;   // monotone: a<b (float) <=> key(a)<key(b) (uint)
}

__global__ void prep_kernel(const float* __restrict__ cb, float* __restrict__ ws) {
    const int k = blockIdx.x * 256 + threadIdx.x;   // 0..1023
    const float4* cb4 = (const float4*)cb;
    float s = 0.f;
#pragma unroll
    for (int j = 0; j < 16; ++j) {
        float4 v = cb4[k * 16 + j];
        s = fmaf(v.x, v.x, s);
        s = fmaf(v.y, v.y, s);
        s = fmaf(v.z, v.z, s);
        s = fmaf(v.w, v.w, s);
    }
    ws[k] = s;             // cnorm: exact R1 chain
    ws[WS_CNT + k] = 0.f;  // zero histogram
    if (k == 0) *(int*)(ws + WS_NFLAG) = 0;

    // swizzled tile stream: tile = k>>4, c = k&15
    _Float16* base = (_Float16*)(ws + WS_CBHL) + (size_t)(k >> 4) * 2048 + (k & 15) * 64;
    const int c = k & 15;
#pragma unroll
    for (int d8 = 0; d8 < 8; ++d8) {
        float4 a = cb4[k * 16 + 2 * d8], b = cb4[k * 16 + 2 * d8 + 1];
        float xf[8] = {a.x, a.y, a.z, a.w, b.x, b.y, b.z, b.w};
        half8 h, lo;
#pragma unroll
        for (int i = 0; i < 8; ++i) {
            _Float16 hi = (_Float16)xf[i];
            h[i] = hi;
            lo[i] = (_Float16)((xf[i] - (float)hi) * 4096.f);  // scaled: no f16 denorm flush
        }
        const int pos = ((d8 + c) & 7) * 8;   // 16B-slot rotation (bank spread)
        *(half8*)(base + pos) = h;
        *(half8*)(base + 1024 + pos) = lo;
    }
}

__launch_bounds__(256, 4)
__global__ void quant_kernel(const float* __restrict__ z,
                             const float* __restrict__ cb,
                             float* __restrict__ out,
                             float* __restrict__ ws) {
    const int t = threadIdx.x, blk = blockIdx.x;
    const int w = t >> 6, l = t & 63;
    const int cl = l & 15, g = l >> 4;
    const int tok0 = blk * 64;
    const int tokL = w * 16 + cl;
    const int tokG = tok0 + tokL;

    __shared__ __align__(16) _Float16 tiles[4][2][2048];  // 4-slot x 2-tile ring, 32KB
    __shared__ __align__(16) float cn_lds[1024];
    __shared__ int win[64];
    __shared__ float lsum[64];

    // ---- stage cnorm to LDS ----
    *(float4*)&cn_lds[t * 4] = *(const float4*)(ws + t * 4);

    // ---- B fragments: ONE token set of 16 (persistent regs; proven) ----
    half8 zh[2], zl[2];
    {
        const float4* z4 = (const float4*)z + (size_t)tokG * 16;
#pragma unroll
        for (int q = 0; q < 2; ++q) {
            float4 a = z4[2 * g + 8 * q], b = z4[2 * g + 8 * q + 1];
            float xf[8] = {a.x, a.y, a.z, a.w, b.x, b.y, b.z, b.w};
#pragma unroll
            for (int i = 0; i < 8; ++i) {
                _Float16 h = (_Float16)xf[i];
                zh[q][i] = h;
                zl[q][i] = (_Float16)((xf[i] - (float)h) * 4096.f);
            }
        }
    }

    // PIN: z-loads + LDS writes done; in-loop vmcnt counts ONLY DMA stream.
    asm volatile("s_waitcnt vmcnt(0) lgkmcnt(0)" ::: "memory");
    __builtin_amdgcn_sched_barrier(0);

    // per-wave DMA src: wave w stages quarter w of each tile (1KB/tile)
    const char* dma_src = (const char*)(ws + WS_CBHL) + w * 1024 + l * 16;
    const int rot = (g + cl) & 7;
    const int o0 = cl * 64 + rot * 8;
    const int o1 = cl * 64 + (rot ^ 4) * 8;

    // prologue: groups 0,1,2 in flight (2 tiles each -> 6 DMAs/wave)
#pragma unroll
    for (int p = 0; p < 3; ++p)
#pragma unroll
        for (int u = 0; u < 2; ++u)
            __builtin_amdgcn_global_load_lds(
                (const __attribute__((address_space(1))) void*)(dma_src + (p * 2 + u) * 4096),
                (__attribute__((address_space(3))) void*)&tiles[p][u][w * 512], 16, 0, 0);

    float d1 = 3.4e38f, d2 = 3.4e38f;
    int idx1 = 0;

#define TILE_COMPUTE(ti, TP)                                                          \
    {                                                                                 \
        const _Float16* tp = (TP);                                                    \
        half8 H0 = *(const half8*)(tp + o0);                                          \
        half8 H1 = *(const half8*)(tp + o1);                                          \
        half8 L0 = *(const half8*)(tp + 1024 + o0);                                   \
        half8 L1 = *(const half8*)(tp + 1024 + o1);                                   \
        float4 cnv = *(const float4*)&cn_lds[(ti) * 16 + 4 * g];                      \
        const float cna[4] = {cnv.x, cnv.y, cnv.z, cnv.w};                            \
        f32x4 a1 = {0.f,0.f,0.f,0.f}, a2 = {0.f,0.f,0.f,0.f};                         \
        a1 = __builtin_amdgcn_mfma_f32_16x16x32_f16(H0, zh[0], a1, 0, 0, 0);          \
        a1 = __builtin_amdgcn_mfma_f32_16x16x32_f16(H1, zh[1], a1, 0, 0, 0);          \
        a2 = __builtin_amdgcn_mfma_f32_16x16x32_f16(H0, zl[0], a2, 0, 0, 0);          \
        a2 = __builtin_amdgcn_mfma_f32_16x16x32_f16(H1, zl[1], a2, 0, 0, 0);          \
        a2 = __builtin_amdgcn_mfma_f32_16x16x32_f16(L0, zh[0], a2, 0, 0, 0);          \
        a2 = __builtin_amdgcn_mfma_f32_16x16x32_f16(L1, zh[1], a2, 0, 0, 0);          \
        _Pragma("unroll")                                                             \
        for (int r = 0; r < 4; ++r) {                                                 \
            float dot = fmaf(a2[r], 2.44140625e-4f, a1[r]);                           \
            float d = fmaf(-2.f, dot, cna[r]);                                        \
            const int kidx = (ti) * 16 + 4 * g + r;                                   \
            bool lt = d < d1;                                                         \
            d2 = fminf(d2, fmaxf(d, d1));                                             \
            idx1 = lt ? kidx : idx1;                                                  \
            d1 = fminf(d1, d);                                                        \
        }                                                                             \
    }

    // phase P: vmcnt (group P landed), barrier, issue group P+3, compute 2 tiles.
#define PHASE(P, SLOT, SLOT2, VM, ISSUE)                                              \
    {                                                                                 \
        asm volatile("s_waitcnt vmcnt(" VM ")" ::: "memory");                         \
        asm volatile("s_barrier" ::: "memory");                                       \
        if (ISSUE) {                                                                  \
            _Pragma("unroll")                                                         \
            for (int u = 0; u < 2; ++u)                                               \
                __builtin_amdgcn_global_load_lds(                                     \
                    (const __attribute__((address_space(1))) void*)(dma_src + (((P) + 3) * 2 + u) * 4096), \
                    (__attribute__((address_space(3))) void*)&tiles[SLOT2][u][w * 512], \
                    16, 0, 0);                                                        \
        }                                                                             \
        TILE_COMPUTE((P) * 2 + 0, &tiles[SLOT][0][0])                                 \
        TILE_COMPUTE((P) * 2 + 1, &tiles[SLOT][1][0])                                 \
    }

    // phases 0..27 (7 x 4, static ring slots), issuing groups 3..30
    for (int i4 = 0; i4 < 28; i4 += 4) {
        PHASE(i4 + 0, 0, 3, "4", 1)
        PHASE(i4 + 1, 1, 0, "4", 1)
        PHASE(i4 + 2, 2, 1, "4", 1)
        PHASE(i4 + 3, 3, 2, "4", 1)
    }
    PHASE(28, 0, 3, "4", 1)   // issues group 31
    PHASE(29, 1, 0, "4", 0)
    PHASE(30, 2, 0, "2", 0)
    PHASE(31, 3, 0, "0", 0)
#undef PHASE
#undef TILE_COMPUTE

    // ---- merge 4 lanes per token (lanes cl, cl+16, cl+32, cl+48) ----
    unsigned long long key = ((unsigned long long)order_key(d1) << 32) | (unsigned)idx1;
#pragma unroll
    for (int off = 16; off <= 32; off <<= 1) {
        unsigned long long ok = __shfl_xor(key, off, 64);
        float od1 = __shfl_xor(d1, off, 64);
        float od2 = __shfl_xor(d2, off, 64);
        d2 = fminf(fminf(d2, od2), fmaxf(d1, od1));  // 2nd-min of union
        d1 = fminf(d1, od1);
        key = ok < key ? ok : key;
    }
    if (l < 16) {
        const int idx = (int)(unsigned)(key & 0xFFFFFFFFull);
        win[tokL] = idx;
        atomicAdd(&ws[WS_CNT + idx], 1.f);   // integer-valued: exact, order-indep
        if (d2 - d1 < MARGIN) {              // near-tie: flag for exact rescore
            int slot = atomicAdd((int*)(ws + WS_NFLAG), 1);
            if (slot < FLAG_CAP)
                ((int*)(ws + WS_FLAGS))[slot] = tokG | (idx << 16);
        }
    }
    __syncthreads();

    // ---- fused epilogue: z_q_bar + commit-loss partial (z re-read, L2-hot) ----
    {
        const int tokr = t >> 2, fb = (t & 3) * 4;   // 4 threads per token
        const int idx = win[tokr];
        const float4* zr = (const float4*)z + (size_t)(tok0 + tokr) * 16;
        const float4* cq = (const float4*)cb + (size_t)idx * 16;
        float4* o4 = (float4*)out + (size_t)(tok0 + tokr) * 16;
        float ss = 0.f;
#pragma unroll
        for (int j = 0; j < 4; ++j) {
            float4 xv = zr[fb + j];
            float4 qv = cq[fb + j];
            float4 ov; float dx;
            dx = qv.x - xv.x; ov.x = xv.x + dx; ss = fmaf(dx, dx, ss);
            dx = qv.y - xv.y; ov.y = xv.y + dx; ss = fmaf(dx, dx, ss);
            dx = qv.z - xv.z; ov.z = xv.z + dx; ss = fmaf(dx, dx, ss);
            dx = qv.w - xv.w; ov.w = xv.w + dx; ss = fmaf(dx, dx, ss);
            o4[fb + j] = ov;
        }
        ss += __shfl_down(ss, 2, 64);   // quadrants: (q0+q2)
        ss += __shfl_down(ss, 1, 64);   // + (q1+q3)
        if ((t & 3) == 0) lsum[tokr] = ss * (1.f / 64.f);
    }
    __syncthreads();
    if (t < 64) {
        float v = lsum[t];
#pragma unroll
        for (int off = 32; off > 0; off >>= 1) v += __shfl_down(v, off, 64);
        if (t == 0) ws[WS_LOSS + blk] = v;
    }
}

// Exact fp32 rescore (R1 chain) for flagged near-ties. One flag per WAVE,
// butterfly reduce, no __syncthreads. 512 blocks = 2048 waves >= nf.
__global__ void rescue_kernel(const float* __restrict__ z,
                              const float* __restrict__ cb,
                              float* __restrict__ out,
                              float* __restrict__ ws) {
    int nf = *(const int*)(ws + WS_NFLAG);
    if (nf > FLAG_CAP) nf = FLAG_CAP;
    const int l = threadIdx.x & 63;
    const int wave = blockIdx.x * (blockDim.x >> 6) + (threadIdx.x >> 6);
    const int nw = gridDim.x * (blockDim.x >> 6);
    const float4* cb4 = (const float4*)cb;

    for (int i = wave; i < nf; i += nw) {
        const int e = ((const int*)(ws + WS_FLAGS))[i];
        const int tok = e & 0xFFFF, oldidx = e >> 16;
        const float4* zr = (const float4*)z + (size_t)tok * 16;
        float4 xv[16];
#pragma unroll
        for (int j = 0; j < 16; ++j) xv[j] = zr[j];   // broadcast load

        unsigned long long bk = ~0ull;
#pragma unroll 4
        for (int q = 0; q < 16; ++q) {
            const int k = l + q * 64;
            const float4* cr = cb4 + (size_t)k * 16;
            float s = 0.f;
#pragma unroll
            for (int j = 0; j < 16; ++j) {
                float4 c = cr[j];
                s = fmaf(xv[j].x, c.x, s);
                s = fmaf(xv[j].y, c.y, s);
                s = fmaf(xv[j].z, c.z, s);
                s = fmaf(xv[j].w, c.w, s);
            }
            float d = fmaf(-2.f, s, ws[k]);   // exact R1 distance
            unsigned long long kk = ((unsigned long long)order_key(d) << 32) | (unsigned)k;
            bk = kk < bk ? kk : bk;
        }
#pragma unroll
        for (int off = 1; off < 64; off <<= 1) {
            unsigned long long o = __shfl_xor(bk, off, 64);
            bk = o < bk ? o : bk;
        }
        const int ni = (int)(unsigned)(bk & 0xFFFFFFFFull);

        if (ni != oldidx) {
            // rewrite z_q_bar (lanes 0-15, one float4 each)
            if (l < 16) {
                float4 xvv = xv[l];
                float4 qv = cb4[(size_t)ni * 16 + l];
                float4 ov; float dx;
                dx = qv.x - xvv.x; ov.x = xvv.x + dx;
                dx = qv.y - xvv.y; ov.y = xvv.y + dx;
                dx = qv.z - xvv.z; ov.z = xvv.z + dx;
                dx = qv.w - xvv.w; ov.w = xvv.w + dx;
                ((float4*)out)[(size_t)tok * 16 + l] = ov;
            }
            // loss delta: lanes 0-3 replicate the quant epilogue's quadrant chains
            float so = 0.f, sn = 0.f;
            if (l < 4) {
#pragma unroll
                for (int j = 0; j < 4; ++j) {
                    float4 xvv = xv[l * 4 + j];
                    float4 qo = cb4[(size_t)oldidx * 16 + l * 4 + j];
                    float4 qn = cb4[(size_t)ni * 16 + l * 4 + j];
                    float dx;
                    dx = qo.x - xvv.x; so = fmaf(dx, dx, so);
                    dx = qo.y - xvv.y; so = fmaf(dx, dx, so);
                    dx = qo.z - xvv.z; so = fmaf(dx, dx, so);
                    dx = qo.w - xvv.w; so = fmaf(dx, dx, so);
                    dx = qn.x - xvv.x; sn = fmaf(dx, dx, sn);
                    dx = qn.y - xvv.y; sn = fmaf(dx, dx, sn);
                    dx = qn.z - xvv.z; sn = fmaf(dx, dx, sn);
                    dx = qn.w - xvv.w; sn = fmaf(dx, dx, sn);
                }
            }
            float so1 = __shfl(so, 1, 64), so2 = __shfl(so, 2, 64), so3 = __shfl(so, 3, 64);
            float sn1 = __shfl(sn, 1, 64), sn2 = __shfl(sn, 2, 64), sn3 = __shfl(sn, 3, 64);
            if (l == 0) {
                float sso = (so + so2) + (so1 + so3);   // match quant shfl tree
                float ssn = (sn + sn2) + (sn1 + sn3);
                atomicAdd(&ws[WS_CNT + oldidx], -1.f);
                atomicAdd(&ws[WS_CNT + ni], 1.f);
                atomicAdd(&ws[WS_LOSS + (tok >> 6)], (ssn - sso) * (1.f / 64.f));
            }
        }
    }
}

// Reduce-only final (shuffle trees; R12/R13-proven logic). 1 block x 1024 thr.
__global__ void final_kernel(const float* __restrict__ ws, float* __restrict__ out) {
    const int t = threadIdx.x;          // 0..1023
    const int l = t & 63, wv = t >> 6;  // 16 waves
    __shared__ float rbuf[16];

#define BLOCK_REDUCE(VAR, EXPR)                                             \
    float VAR;                                                              \
    {                                                                       \
        float v_ = (EXPR);                                                  \
        _Pragma("unroll")                                                   \
        for (int off = 32; off > 0; off >>= 1) v_ += __shfl_down(v_, off, 64); \
        if (l == 0) rbuf[wv] = v_;                                          \
        __syncthreads();                                                    \
        float r_ = (t < 16) ? rbuf[t] : 0.f;                                \
        if (wv == 0) {                                                      \
            _Pragma("unroll")                                               \
            for (int off = 8; off > 0; off >>= 1) r_ += __shfl_down(r_, off, 64); \
            if (l == 0) rbuf[0] = r_;                                       \
        }                                                                   \
        __syncthreads();                                                    \
        VAR = rbuf[0];                                                      \
        __syncthreads();                                                    \
    }

    const float c = ws[WS_CNT + t];
    BLOCK_REDUCE(totraw, c)
    const float total = fmaxf(totraw, 1e-6f);
    const float p = c / total;
    BLOCK_REDUCE(ent, p * logf(p + 1e-7f))
    BLOCK_REDUCE(used, (c >= 1.f) ? 1.f : 0.f)
    BLOCK_REDUCE(loss, ws[WS_LOSS + t])
#undef BLOCK_REDUCE

    if (t == 0) {
        out[OUT_SCALARS + 0] = loss * (1.f / (float)NTOK);
        out[OUT_SCALARS + 1] = expf(-ent);
        out[OUT_SCALARS + 2] = used * (1.f / (float)KCODE);
    }
}

extern "C" void kernel_launch(void* const* d_in, const int* in_sizes, int n_in,
                              void* d_out, int out_size, void* d_ws, size_t ws_size,
                              hipStream_t stream) {
    const float* z  = (const float*)d_in[0];
    const float* cb = (const float*)d_in[1];
    float* out = (float*)d_out;
    float* ws  = (float*)d_ws;   // ~344 KB used

    prep_kernel  <<<4, 256, 0, stream>>>(cb, ws);
    quant_kernel <<<NTOK / 64, 256, 0, stream>>>(z, cb, out, ws);
    rescue_kernel<<<512, 256, 0, stream>>>(z, cb, out, ws);
    final_kernel <<<1, 1024, 0, stream>>>(ws, out);
}

// Round 21
// 80.273 us; speedup vs baseline: 1.4943x; 1.4943x over previous
//
#include <hip/hip_runtime.h>

// QuantizeEMAReset forward (eval): VQ quantize + commit loss + perplexity/usage.
// z: [16,4096,64] fp32 -> N=65536 tokens, C=64. codebook: [1024,64] fp32.
// out: [z_q_bar (4194304 f32), commit_loss, ppl, usage] flat.
//
// R21 = R14 VERBATIM (best measured configuration: 80.35us total, absmax 0.0).
// 20-round ledger: quant plateaus at 69-75us across 7 sync structures (R7,
// R11, R13, R14, R17, R18, R19); separate rescue dispatches cost 40-260us
// regardless of parallelism (R5/R7/R11/R12/R19/R20) -> in-lane O(2) rescue
// (R13) is the only free exactness mechanism; 2-frag-set / 32x32 register
// profiles are quarantined (R9/R10/R15 unexplained ppl corruption).
// Structure: barrier-free main loop, wave-private 3-slot LDS rings (each wave
// DMAs its own 4KB tile, 2 in flight, vmcnt(4), zero s_barrier in loop),
// fp16-split 6-MFMA distances, keyed top-2 + in-lane exact fp32 rescue.
//
// ws float-index map:
//   [0,1024)       cnorm
//   [1024,2048)    counts
//   [2048,3072)    loss partials (1024 blocks)
//   [20480,86016)  cbhl tile stream: 64 tiles x 2048 halves (hi 1KB | lo 1KB)

typedef _Float16 half8 __attribute__((ext_vector_type(8)));
typedef float f32x4 __attribute__((ext_vector_type(4)));

#define NTOK 65536
#define KCODE 1024
#define OUT_SCALARS 4194304
#define MARGIN 1e-3f

#define WS_CNT   1024
#define WS_LOSS  2048
#define WS_CBHL  20480

static __device__ __forceinline__ unsigned int order_key(float f) {
    unsigned int u = __float_as_uint(f);
    unsigned int mask = (u >> 31) ? 0xFFFFFFFFu : 0x80000000u;
    return u ^ mask;   // monotone: a<b (float) <=> key(a)<key(b) (uint)
}
static __device__ __forceinline__ float key_to_float(unsigned int k) {
    unsigned int u = (k & 0x80000000u) ? (k ^ 0x80000000u) : ~k;
    return __uint_as_float(u);   // inverse of order_key
}
static __device__ __forceinline__ unsigned long long umin64(unsigned long long a,
                                                            unsigned long long b) {
    return a < b ? a : b;
}
static __device__ __forceinline__ unsigned long long umax64(unsigned long long a,
                                                            unsigned long long b) {
    return a > b ? a : b;
}

__global__ void prep_kernel(const float* __restrict__ cb, float* __restrict__ ws) {
    const int k = blockIdx.x * 256 + threadIdx.x;   // 0..1023
    const float4* cb4 = (const float4*)cb;
    float s = 0.f;
#pragma unroll
    for (int j = 0; j < 16; ++j) {
        float4 v = cb4[k * 16 + j];
        s = fmaf(v.x, v.x, s);
        s = fmaf(v.y, v.y, s);
        s = fmaf(v.z, v.z, s);
        s = fmaf(v.w, v.w, s);
    }
    ws[k] = s;             // cnorm: exact R1 chain
    ws[WS_CNT + k] = 0.f;  // zero histogram

    // swizzled tile stream: tile = k>>4, c = k&15
    _Float16* base = (_Float16*)(ws + WS_CBHL) + (size_t)(k >> 4) * 2048 + (k & 15) * 64;
    const int c = k & 15;
#pragma unroll
    for (int d8 = 0; d8 < 8; ++d8) {
        float4 a = cb4[k * 16 + 2 * d8], b = cb4[k * 16 + 2 * d8 + 1];
        float xf[8] = {a.x, a.y, a.z, a.w, b.x, b.y, b.z, b.w};
        half8 h, lo;
#pragma unroll
        for (int i = 0; i < 8; ++i) {
            _Float16 hi = (_Float16)xf[i];
            h[i] = hi;
            lo[i] = (_Float16)((xf[i] - (float)hi) * 4096.f);  // scaled: no f16 denorm flush
        }
        const int pos = ((d8 + c) & 7) * 8;   // 16B-slot rotation (bank spread)
        *(half8*)(base + pos) = h;
        *(half8*)(base + 1024 + pos) = lo;
    }
}

__launch_bounds__(256, 3)
__global__ void quant_kernel(const float* __restrict__ z,
                             const float* __restrict__ cb,
                             float* __restrict__ out,
                             float* __restrict__ ws) {
    const int t = threadIdx.x, blk = blockIdx.x;
    const int w = t >> 6, l = t & 63;
    const int cl = l & 15, g = l >> 4;
    const int tok0 = blk * 64;
    const int tokL = w * 16 + cl;
    const int tokG = tok0 + tokL;

    __shared__ __align__(16) _Float16 ring[4][3][2048];  // wave-private 3-slot rings, 48KB
    __shared__ __align__(16) float cn_lds[1024];
    __shared__ int win[64];
    __shared__ float lsum[64];

    // ---- stage cnorm to LDS ----
    *(float4*)&cn_lds[t * 4] = *(const float4*)(ws + t * 4);

    // ---- B fragments: ONE token set of 16 (persistent regs; proven) ----
    half8 zh[2], zl[2];
    {
        const float4* z4 = (const float4*)z + (size_t)tokG * 16;
#pragma unroll
        for (int q = 0; q < 2; ++q) {
            float4 a = z4[2 * g + 8 * q], b = z4[2 * g + 8 * q + 1];
            float xf[8] = {a.x, a.y, a.z, a.w, b.x, b.y, b.z, b.w};
#pragma unroll
            for (int i = 0; i < 8; ++i) {
                _Float16 h = (_Float16)xf[i];
                zh[q][i] = h;
                zl[q][i] = (_Float16)((xf[i] - (float)h) * 4096.f);
            }
        }
    }

    // PIN: z-loads + own LDS writes complete; in-loop vmcnt counts ONLY DMAs.
    asm volatile("s_waitcnt vmcnt(0) lgkmcnt(0)" ::: "memory");
    __builtin_amdgcn_sched_barrier(0);
    __syncthreads();   // cn_lds visible to all waves (ONLY block barrier pre-loop)

    // per-lane DMA src: each wave stages FULL tiles into its own ring
    const char* dma_src = (const char*)(ws + WS_CBHL) + l * 16;
    const int rot = (g + cl) & 7;
    const int o0 = cl * 64 + rot * 8;
    const int o1 = cl * 64 + (rot ^ 4) * 8;

    // prologue: tiles 0,1 in flight (8 DMAs/wave)
#pragma unroll
    for (int p = 0; p < 2; ++p)
#pragma unroll
        for (int q = 0; q < 4; ++q)
            __builtin_amdgcn_global_load_lds(
                (const __attribute__((address_space(1))) void*)(dma_src + p * 4096 + q * 1024),
                (__attribute__((address_space(3))) void*)&ring[w][p][q * 512], 16, 0, 0);

    float d1 = 3.4e38f, d2 = 3.4e38f;
    int idx1 = 0, idx2 = 0;

    // tile T: wait own tile-T DMAs (vmcnt), read frags, issue tile T+2, compute.
    // NO s_barrier: ring is wave-private; asm "memory" orders LDS ops so the
    // T+2 DMA (slot (T+2)%3, last read at T-1) can't hoist above prior reads.
#define TILE_BODY(ti, SLOT, VM, ISSUE)                                                \
    {                                                                                 \
        asm volatile("s_waitcnt vmcnt(" VM ")" ::: "memory");                         \
        const _Float16* tp = &ring[w][SLOT][0];                                       \
        half8 H0 = *(const half8*)(tp + o0);                                          \
        half8 H1 = *(const half8*)(tp + o1);                                          \
        half8 L0 = *(const half8*)(tp + 1024 + o0);                                   \
        half8 L1 = *(const half8*)(tp + 1024 + o1);                                   \
        float4 cnv = *(const float4*)&cn_lds[(ti) * 16 + 4 * g];                      \
        const float cna[4] = {cnv.x, cnv.y, cnv.z, cnv.w};                            \
        if (ISSUE) {                                                                  \
            _Pragma("unroll")                                                         \
            for (int q = 0; q < 4; ++q)                                               \
                __builtin_amdgcn_global_load_lds(                                     \
                    (const __attribute__((address_space(1))) void*)(dma_src + ((ti) + 2) * 4096 + q * 1024), \
                    (__attribute__((address_space(3))) void*)&ring[w][((SLOT) + 2) % 3][q * 512], \
                    16, 0, 0);                                                        \
        }                                                                             \
        f32x4 a1 = {0.f,0.f,0.f,0.f}, a2 = {0.f,0.f,0.f,0.f};                         \
        a1 = __builtin_amdgcn_mfma_f32_16x16x32_f16(H0, zh[0], a1, 0, 0, 0);          \
        a1 = __builtin_amdgcn_mfma_f32_16x16x32_f16(H1, zh[1], a1, 0, 0, 0);          \
        a2 = __builtin_amdgcn_mfma_f32_16x16x32_f16(H0, zl[0], a2, 0, 0, 0);          \
        a2 = __builtin_amdgcn_mfma_f32_16x16x32_f16(H1, zl[1], a2, 0, 0, 0);          \
        a2 = __builtin_amdgcn_mfma_f32_16x16x32_f16(L0, zh[0], a2, 0, 0, 0);          \
        a2 = __builtin_amdgcn_mfma_f32_16x16x32_f16(L1, zh[1], a2, 0, 0, 0);          \
        _Pragma("unroll")                                                             \
        for (int r = 0; r < 4; ++r) {                                                 \
            float dot = fmaf(a2[r], 2.44140625e-4f, a1[r]);                           \
            float d = fmaf(-2.f, dot, cna[r]);                                        \
            const int kidx = (ti) * 16 + 4 * g + r;                                   \
            bool lt = d < d1;                                                         \
            bool mid = d < d2;                                                        \
            idx2 = lt ? idx1 : (mid ? kidx : idx2);   /* old values: order matters */ \
            d2 = fminf(d2, fmaxf(d, d1));                                             \
            idx1 = lt ? kidx : idx1;                                                  \
            d1 = fminf(d1, d);                                                        \
        }                                                                             \
    }

    // tiles 0..59 (20 x 3, static ring slots), issuing tiles 2..61
    for (int i3 = 0; i3 < 60; i3 += 3) {
        TILE_BODY(i3 + 0, 0, "4", 1)
        TILE_BODY(i3 + 1, 1, "4", 1)
        TILE_BODY(i3 + 2, 2, "4", 1)
    }
    TILE_BODY(60, 0, "4", 1)   // issues tile 62
    TILE_BODY(61, 1, "4", 1)   // issues tile 63
    TILE_BODY(62, 2, "4", 0)
    TILE_BODY(63, 0, "0", 0)
#undef TILE_BODY

    // ---- keyed top-2 merge across the 4 lanes of each token (xor 16, 32) ----
    unsigned long long k1 = ((unsigned long long)order_key(d1) << 32) | (unsigned)idx1;
    unsigned long long k2 = ((unsigned long long)order_key(d2) << 32) | (unsigned)idx2;
#pragma unroll
    for (int off = 16; off <= 32; off <<= 1) {
        unsigned long long ok1 = __shfl_xor(k1, off, 64);
        unsigned long long ok2 = __shfl_xor(k2, off, 64);
        unsigned long long lo = umin64(k1, ok1);
        unsigned long long hi = umax64(k1, ok1);
        k2 = umin64(hi, umin64(k2, ok2));
        k1 = lo;
    }

    if (l < 16) {
        int fidx = (int)(unsigned)(k1 & 0xFFFFFFFFull);
        const float d1f = key_to_float((unsigned)(k1 >> 32));
        const float d2f = key_to_float((unsigned)(k2 >> 32));
        if (d2f - d1f < MARGIN) {
            // exact fp32 rescore of the two candidates (bit-exact R1 chain)
            const int ia = fidx;
            const int ib = (int)(unsigned)(k2 & 0xFFFFFFFFull);
            const float4* zr = (const float4*)z + (size_t)tokG * 16;
            const float4* ca = (const float4*)cb + (size_t)ia * 16;
            const float4* cbp = (const float4*)cb + (size_t)ib * 16;
            float sa = 0.f, sb = 0.f;
#pragma unroll
            for (int j = 0; j < 16; ++j) {
                float4 xv = zr[j];
                float4 va = ca[j], vb = cbp[j];
                sa = fmaf(xv.x, va.x, sa); sb = fmaf(xv.x, vb.x, sb);
                sa = fmaf(xv.y, va.y, sa); sb = fmaf(xv.y, vb.y, sb);
                sa = fmaf(xv.z, va.z, sa); sb = fmaf(xv.z, vb.z, sb);
                sa = fmaf(xv.w, va.w, sa); sb = fmaf(xv.w, vb.w, sb);
            }
            const float ea = fmaf(-2.f, sa, cn_lds[ia]);   // exact R1 distance
            const float eb = fmaf(-2.f, sb, cn_lds[ib]);
            const unsigned long long ka = ((unsigned long long)order_key(ea) << 32) | (unsigned)ia;
            const unsigned long long kb = ((unsigned long long)order_key(eb) << 32) | (unsigned)ib;
            fidx = (int)(unsigned)(umin64(ka, kb) & 0xFFFFFFFFull);
        }
        win[tokL] = fidx;
        atomicAdd(&ws[WS_CNT + fidx], 1.f);   // integer-valued: exact, order-indep
    }
    __syncthreads();

    // ---- fused epilogue: z_q_bar + commit-loss partial (z re-read, L2-hot) ----
    {
        const int tokr = t >> 2, fb = (t & 3) * 4;   // 4 threads per token
        const int idx = win[tokr];
        const float4* zr = (const float4*)z + (size_t)(tok0 + tokr) * 16;
        const float4* cq = (const float4*)cb + (size_t)idx * 16;
        float4* o4 = (float4*)out + (size_t)(tok0 + tokr) * 16;
        float ss = 0.f;
#pragma unroll
        for (int j = 0; j < 4; ++j) {
            float4 xv = zr[fb + j];
            float4 qv = cq[fb + j];
            float4 ov; float dx;
            dx = qv.x - xv.x; ov.x = xv.x + dx; ss = fmaf(dx, dx, ss);
            dx = qv.y - xv.y; ov.y = xv.y + dx; ss = fmaf(dx, dx, ss);
            dx = qv.z - xv.z; ov.z = xv.z + dx; ss = fmaf(dx, dx, ss);
            dx = qv.w - xv.w; ov.w = xv.w + dx; ss = fmaf(dx, dx, ss);
            o4[fb + j] = ov;
        }
        ss += __shfl_down(ss, 2, 64);   // quadrants: (q0+q2)
        ss += __shfl_down(ss, 1, 64);   // + (q1+q3)
        if ((t & 3) == 0) lsum[tokr] = ss * (1.f / 64.f);
    }
    __syncthreads();
    if (t < 64) {
        float v = lsum[t];
#pragma unroll
        for (int off = 32; off > 0; off >>= 1) v += __shfl_down(v, off, 64);
        if (t == 0) ws[WS_LOSS + blk] = v;
    }
}

// Reduce-only final (shuffle trees; R12/R13-proven logic). 1 block x 1024 thr.
__global__ void final_kernel(const float* __restrict__ ws, float* __restrict__ out) {
    const int t = threadIdx.x;          // 0..1023
    const int l = t & 63, wv = t >> 6;  // 16 waves
    __shared__ float rbuf[16];

#define BLOCK_REDUCE(VAR, EXPR)                                             \
    float VAR;                                                              \
    {                                                                       \
        float v_ = (EXPR);                                                  \
        _Pragma("unroll")                                                   \
        for (int off = 32; off > 0; off >>= 1) v_ += __shfl_down(v_, off, 64); \
        if (l == 0) rbuf[wv] = v_;                                          \
        __syncthreads();                                                    \
        float r_ = (t < 16) ? rbuf[t] : 0.f;                                \
        if (wv == 0) {                                                      \
            _Pragma("unroll")                                               \
            for (int off = 8; off > 0; off >>= 1) r_ += __shfl_down(r_, off, 64); \
            if (l == 0) rbuf[0] = r_;                                       \
        }                                                                   \
        __syncthreads();                                                    \
        VAR = rbuf[0];                                                      \
        __syncthreads();                                                    \
    }

    const float c = ws[WS_CNT + t];
    BLOCK_REDUCE(totraw, c)
    const float total = fmaxf(totraw, 1e-6f);
    const float p = c / total;
    BLOCK_REDUCE(ent, p * logf(p + 1e-7f))
    BLOCK_REDUCE(used, (c >= 1.f) ? 1.f : 0.f)
    BLOCK_REDUCE(loss, ws[WS_LOSS + t])
#undef BLOCK_REDUCE

    if (t == 0) {
        out[OUT_SCALARS + 0] = loss * (1.f / (float)NTOK);
        out[OUT_SCALARS + 1] = expf(-ent);
        out[OUT_SCALARS + 2] = used * (1.f / (float)KCODE);
    }
}

extern "C" void kernel_launch(void* const* d_in, const int* in_sizes, int n_in,
                              void* d_out, int out_size, void* d_ws, size_t ws_size,
                              hipStream_t stream) {
    const float* z  = (const float*)d_in[0];
    const float* cb = (const float*)d_in[1];
    float* out = (float*)d_out;
    float* ws  = (float*)d_ws;   // ~344 KB used

    prep_kernel <<<4, 256, 0, stream>>>(cb, ws);
    quant_kernel<<<NTOK / 64, 256, 0, stream>>>(z, cb, out, ws);
    final_kernel<<<1, 1024, 0, stream>>>(ws, out);
}